// Round 9
// baseline (383.961 us; speedup 1.0000x reference)
//
#include <hip/hip_runtime.h>
#include <hip/hip_fp16.h>

#define N_NODES 100000
#define IN_CH 128
#define OUT_CH 64
#define HID 128
#define N_EDGES 1600000

// CSR build: 782 buckets of 128 dst-nodes (dst>>7). 99999>>7 = 781.
#define NBUCK 782
#define BBLK  128               // binning blocks (fat: per-(block,bucket) run ~16 edges = 64 B line)
#define CHUNK (N_EDGES / BBLK)  // 12500 edges per binning block

typedef _Float16 half8 __attribute__((ext_vector_type(8)));
typedef float floatx4 __attribute__((ext_vector_type(4)));

// ---------------- CSR pass 1: bucket totals (per-block LDS hist -> global atomicAdd) ----------

__global__ __launch_bounds__(512) void k_hist(const int* __restrict__ dst, int* __restrict__ btot) {
    __shared__ int lh[NBUCK];
    int t = threadIdx.x;
    int blk = blockIdx.x;
    for (int i = t; i < NBUCK; i += 512) lh[i] = 0;
    __syncthreads();
    int base = blk * CHUNK;
    for (int i = base + t; i < base + CHUNK; i += 512) {
        atomicAdd(&lh[dst[i] >> 7], 1);
    }
    __syncthreads();
    for (int i = t; i < NBUCK; i += 512) {
        int c = lh[i];
        if (c) atomicAdd(&btot[i], c);
    }
}

// ---------------- CSR pass 2: block 0 scans bucket totals; blocks 1..16 do weight prep --------

__global__ __launch_bounds__(1024) void k_bases(const int* __restrict__ btot,
                                                int* __restrict__ bbase,
                                                int* __restrict__ bcur,
                                                const float* __restrict__ W1,
                                                const float* __restrict__ Wmu,
                                                const float* __restrict__ Wls,
                                                __half* __restrict__ W1t,
                                                __half* __restrict__ Wct) {
    int t = threadIdx.x;
    if (blockIdx.x > 0) {  // weight prep: 16 blocks x 1024 = 16384 = 128*128
        int i = (blockIdx.x - 1) * 1024 + t;
        int n = i >> 7, k = i & 127;
        W1t[i] = __float2half(W1[k * 128 + n]);
        Wct[i] = __float2half(n < 64 ? Wmu[k * 64 + n] : Wls[k * 64 + (n - 64)]);
        return;
    }
    __shared__ int tmp[1024];
    int v = (t < NBUCK) ? btot[t] : 0;
    tmp[t] = v;
    __syncthreads();
    for (int off = 1; off < 1024; off <<= 1) {
        int u = (t >= off) ? tmp[t - off] : 0;
        __syncthreads();
        tmp[t] += u;
        __syncthreads();
    }
    if (t < NBUCK) {
        int excl = tmp[t] - v;
        bbase[t] = excl;
        bcur[t] = excl;
    }
    if (t == NBUCK - 1) bbase[NBUCK] = tmp[t];  // = N_EDGES
}

// ---------------- CSR pass 3: scatter edges into bucket-contiguous array ----------------
// Per block: LDS-count chunk -> reserve per-bucket ranges (1 global atomic per (block,bucket))
// -> scatter. binned packs src (17 bits) | dst&127 (bits 17..23). 128 fat blocks -> per-bucket
// runs ~16 edges = 64 B = full-line writes.

__global__ __launch_bounds__(512) void k_binscatter(const int* __restrict__ src,
                                                    const int* __restrict__ dst,
                                                    int* __restrict__ bcur,
                                                    int* __restrict__ binned) {
    __shared__ int cnt[NBUCK];
    __shared__ int base[NBUCK];
    int t = threadIdx.x;
    int blk = blockIdx.x;
    for (int i = t; i < NBUCK; i += 512) cnt[i] = 0;
    __syncthreads();
    int cbase = blk * CHUNK;
    for (int i = cbase + t; i < cbase + CHUNK; i += 512) {
        atomicAdd(&cnt[dst[i] >> 7], 1);
    }
    __syncthreads();
    for (int i = t; i < NBUCK; i += 512) {
        int c = cnt[i];
        if (c) base[i] = atomicAdd(&bcur[i], c);
        cnt[i] = 0;  // reuse as cursor
    }
    __syncthreads();
    for (int i = cbase + t; i < cbase + CHUNK; i += 512) {
        int d = dst[i];
        int s = src[i];
        int b = d >> 7;
        int pos = base[b] + atomicAdd(&cnt[b], 1);
        binned[pos] = s | ((d & 127) << 17);
    }
}

// ---------------- CSR pass 4 + cast fused: per-bucket degree/scan/fill, then cast its 128
// nodes' x rows (64 KB contiguous) into pre-scaled fp16 using the in-LDS dinv. ----------------

__global__ __launch_bounds__(256) void k_bucket(const int* __restrict__ binned,
                                                const int* __restrict__ bbase,
                                                int* __restrict__ row_start,
                                                float* __restrict__ dinv,
                                                int* __restrict__ csr_src,
                                                const float* __restrict__ x,
                                                __half* __restrict__ xs) {
    __shared__ int cnt[128];
    __shared__ int ps[128];
    __shared__ int cur[128];
    __shared__ float ldv[128];
    int b = blockIdx.x;
    int t = threadIdx.x;
    int start = bbase[b];
    int end = bbase[b + 1];
    if (t < 128) cnt[t] = 0;
    if (b == NBUCK - 1 && t == 0) row_start[N_NODES] = N_EDGES;  // sentinel
    __syncthreads();
    for (int i = start + t; i < end; i += 256) {
        atomicAdd(&cnt[(binned[i] >> 17) & 127], 1);
    }
    __syncthreads();
    int c = (t < 128) ? cnt[t] : 0;
    if (t < 128) ps[t] = c;
    __syncthreads();
    for (int o = 1; o < 128; o <<= 1) {
        int u = (t < 128 && t >= o) ? ps[t - o] : 0;
        __syncthreads();
        if (t < 128) ps[t] += u;
        __syncthreads();
    }
    if (t < 128) {
        int e = start + ps[t] - c;
        cur[t] = e;
        float d = rsqrtf((float)(c + 1));
        ldv[t] = d;
        int node = (b << 7) + t;
        if (node < N_NODES) {
            row_start[node] = e;
            dinv[node] = d;
        }
    }
    __syncthreads();
    for (int i = start + t; i < end; i += 256) {
        int v = binned[i];
        int p = atomicAdd(&cur[(v >> 17) & 127], 1);
        csr_src[p] = v & 0x1FFFF;
    }
    // fused cast: xs[node] = fp16(dinv[node] * x[node]) for this bucket's 128 nodes
    int nb0 = b << 7;
    for (int i = t; i < 128 * 32; i += 256) {     // float4 groups: 32 per node row
        int ln = i >> 5;
        int node = nb0 + ln;
        if (node >= N_NODES) break;
        float4 v = ((const float4*)x)[(size_t)node * 32 + (i & 31)];
        float d = ldv[ln];
        size_t o = (size_t)node * 64 + (size_t)(i & 31) * 2;  // half2 units
        ((__half2*)xs)[o]     = __floats2half2_rn(d * v.x, d * v.y);
        ((__half2*)xs)[o + 1] = __floats2half2_rn(d * v.z, d * v.w);
    }
}

// ---------------- aggregation (round-0 proven), split into node-range halves ----------------
// row-major [N][128] fp16 pre-scaled; one wave per node; lane = channel pair; unroll-8.
// Split in two 50k dispatches so the rocprof top-5 bar drops to ~31 µs (tail diagnostics).

__global__ __launch_bounds__(256) void k_agg(const __half* __restrict__ in, __half* __restrict__ out,
                                             const int* __restrict__ csr_src,
                                             const int* __restrict__ row_start,
                                             const float* __restrict__ dinv,
                                             int nbase) {
    int w = nbase + ((blockIdx.x * 256 + threadIdx.x) >> 6);
    int lane = threadIdx.x & 63;
    int beg = row_start[w];
    int cnt = row_start[w + 1] - beg;
    float di = dinv[w];
    float2 acc = __half22float2(((const __half2*)(in + (size_t)w * 128))[lane]);  // self term
    int j = 0;
    for (; j + 7 < cnt; j += 8) {
        int s0 = csr_src[beg + j];
        int s1 = csr_src[beg + j + 1];
        int s2 = csr_src[beg + j + 2];
        int s3 = csr_src[beg + j + 3];
        int s4 = csr_src[beg + j + 4];
        int s5 = csr_src[beg + j + 5];
        int s6 = csr_src[beg + j + 6];
        int s7 = csr_src[beg + j + 7];
        float2 v0 = __half22float2(((const __half2*)(in + (size_t)s0 * 128))[lane]);
        float2 v1 = __half22float2(((const __half2*)(in + (size_t)s1 * 128))[lane]);
        float2 v2 = __half22float2(((const __half2*)(in + (size_t)s2 * 128))[lane]);
        float2 v3 = __half22float2(((const __half2*)(in + (size_t)s3 * 128))[lane]);
        float2 v4 = __half22float2(((const __half2*)(in + (size_t)s4 * 128))[lane]);
        float2 v5 = __half22float2(((const __half2*)(in + (size_t)s5 * 128))[lane]);
        float2 v6 = __half22float2(((const __half2*)(in + (size_t)s6 * 128))[lane]);
        float2 v7 = __half22float2(((const __half2*)(in + (size_t)s7 * 128))[lane]);
        acc.x += v0.x + v1.x + v2.x + v3.x + v4.x + v5.x + v6.x + v7.x;
        acc.y += v0.y + v1.y + v2.y + v3.y + v4.y + v5.y + v6.y + v7.y;
    }
    for (; j + 3 < cnt; j += 4) {
        int s0 = csr_src[beg + j];
        int s1 = csr_src[beg + j + 1];
        int s2 = csr_src[beg + j + 2];
        int s3 = csr_src[beg + j + 3];
        float2 v0 = __half22float2(((const __half2*)(in + (size_t)s0 * 128))[lane]);
        float2 v1 = __half22float2(((const __half2*)(in + (size_t)s1 * 128))[lane]);
        float2 v2 = __half22float2(((const __half2*)(in + (size_t)s2 * 128))[lane]);
        float2 v3 = __half22float2(((const __half2*)(in + (size_t)s3 * 128))[lane]);
        acc.x += v0.x + v1.x + v2.x + v3.x;
        acc.y += v0.y + v1.y + v2.y + v3.y;
    }
    for (; j < cnt; j++) {
        int s0 = csr_src[beg + j];
        float2 v0 = __half22float2(((const __half2*)(in + (size_t)s0 * 128))[lane]);
        acc.x += v0.x;
        acc.y += v0.y;
    }
    ((__half2*)(out + (size_t)w * 128))[lane] = __floats2half2_rn(di * acc.x, di * acc.y);
}

// ---------------- GEMM1 (MFMA): H = dinv * relu_normalize(relu(A @ W1 + b1)) ----------------

__global__ __launch_bounds__(256) void k_gemm1(const __half* __restrict__ A,
                                               const __half* __restrict__ Wt,
                                               const float* __restrict__ b,
                                               const float* __restrict__ dinv,
                                               __half* __restrict__ H) {
    int t = threadIdx.x;
    int wv = t >> 6;
    int lane = t & 63;
    int m16 = lane & 15;
    int quad = lane >> 4;
    int row = blockIdx.x * 64 + wv * 16 + m16;
    floatx4 acc[8];
    #pragma unroll
    for (int tt = 0; tt < 8; tt++) acc[tt] = (floatx4){0.f, 0.f, 0.f, 0.f};
    #pragma unroll
    for (int kk = 0; kk < 4; kk++) {
        half8 a = *(const half8*)(A + (size_t)row * 128 + kk * 32 + quad * 8);
        #pragma unroll
        for (int tt = 0; tt < 8; tt++) {
            half8 bf = *(const half8*)(Wt + (size_t)(tt * 16 + m16) * 128 + kk * 32 + quad * 8);
            acc[tt] = __builtin_amdgcn_mfma_f32_16x16x32_f16(a, bf, acc[tt], 0, 0, 0);
        }
    }
    float bias[8];
    #pragma unroll
    for (int tt = 0; tt < 8; tt++) bias[tt] = b[tt * 16 + m16];
    int rbase = blockIdx.x * 64 + wv * 16 + quad * 4;
    #pragma unroll
    for (int r = 0; r < 4; r++) {
        int rw = rbase + r;
        float vv[8];
        float ssq = 0.f;
        #pragma unroll
        for (int tt = 0; tt < 8; tt++) {
            float v = fmaxf(acc[tt][r] + bias[tt], 0.f);
            vv[tt] = v;
            ssq += v * v;
        }
        ssq += __shfl_xor(ssq, 1, 64);
        ssq += __shfl_xor(ssq, 2, 64);
        ssq += __shfl_xor(ssq, 4, 64);
        ssq += __shfl_xor(ssq, 8, 64);
        float s = 1.0f / fmaxf(sqrtf(ssq), 1e-12f);
        if (rw < N_NODES) {
            float sc = s * dinv[rw];  // pre-scale for the next aggregation
            #pragma unroll
            for (int tt = 0; tt < 8; tt++) {
                H[(size_t)rw * 128 + tt * 16 + m16] = __float2half(vv[tt] * sc);
            }
        }
    }
}

// ---------------- GEMM2 (MFMA): out = [ Y2@Wmu+bmu | Y2@Wls+bls ] ----------------

__global__ __launch_bounds__(256) void k_gemm2(const __half* __restrict__ A,
                                               const __half* __restrict__ Wt,
                                               const float* __restrict__ bmu,
                                               const float* __restrict__ bls,
                                               float* __restrict__ out) {
    int t = threadIdx.x;
    int wv = t >> 6;
    int lane = t & 63;
    int m16 = lane & 15;
    int quad = lane >> 4;
    int row = blockIdx.x * 64 + wv * 16 + m16;
    floatx4 acc[8];
    #pragma unroll
    for (int tt = 0; tt < 8; tt++) acc[tt] = (floatx4){0.f, 0.f, 0.f, 0.f};
    #pragma unroll
    for (int kk = 0; kk < 4; kk++) {
        half8 a = *(const half8*)(A + (size_t)row * 128 + kk * 32 + quad * 8);
        #pragma unroll
        for (int tt = 0; tt < 8; tt++) {
            half8 bf = *(const half8*)(Wt + (size_t)(tt * 16 + m16) * 128 + kk * 32 + quad * 8);
            acc[tt] = __builtin_amdgcn_mfma_f32_16x16x32_f16(a, bf, acc[tt], 0, 0, 0);
        }
    }
    float bias[8];
    #pragma unroll
    for (int tt = 0; tt < 8; tt++)
        bias[tt] = (tt < 4) ? bmu[tt * 16 + m16] : bls[(tt - 4) * 16 + m16];
    int rbase = blockIdx.x * 64 + wv * 16 + quad * 4;
    #pragma unroll
    for (int r = 0; r < 4; r++) {
        int rw = rbase + r;
        if (rw < N_NODES) {
            #pragma unroll
            for (int tt = 0; tt < 4; tt++)
                out[(size_t)rw * 64 + tt * 16 + m16] = acc[tt][r] + bias[tt];
            #pragma unroll
            for (int tt = 4; tt < 8; tt++)
                out[(size_t)N_NODES * 64 + (size_t)rw * 64 + (tt - 4) * 16 + m16] = acc[tt][r] + bias[tt];
        }
    }
}

// ---------------- launch ----------------

extern "C" void kernel_launch(void* const* d_in, const int* in_sizes, int n_in,
                              void* d_out, int out_size, void* d_ws, size_t ws_size,
                              hipStream_t stream) {
    const float* x   = (const float*)d_in[0];
    const int*  eidx = (const int*)d_in[1];
    const float* W1  = (const float*)d_in[2];
    const float* b1  = (const float*)d_in[3];
    const float* Wmu = (const float*)d_in[4];
    const float* bmu = (const float*)d_in[5];
    const float* Wls = (const float*)d_in[6];
    const float* bls = (const float*)d_in[7];
    float* out = (float*)d_out;
    const int* e_src = eidx;
    const int* e_dst = eidx + N_EDGES;

    char* ws = (char*)d_ws;
    size_t off_b = 0;
    auto alloc = [&](size_t n) -> void* {
        void* p = ws + off_b;
        off_b += (n + 255) & ~(size_t)255;
        return p;
    };
    float*  dinv      = (float*)alloc((size_t)N_NODES * sizeof(float));
    int*    row_start = (int*)alloc((size_t)(N_NODES + 1) * sizeof(int));
    int*    btot      = (int*)alloc((size_t)NBUCK * sizeof(int));
    int*    bbase     = (int*)alloc((size_t)(NBUCK + 1) * sizeof(int));
    int*    bcur      = (int*)alloc((size_t)NBUCK * sizeof(int));
    int*    csr_src   = (int*)alloc((size_t)N_EDGES * sizeof(int));
    int*    binned    = (int*)alloc((size_t)N_EDGES * sizeof(int));
    __half* W1t       = (__half*)alloc((size_t)128 * 128 * sizeof(__half));
    __half* Wct       = (__half*)alloc((size_t)128 * 128 * sizeof(__half));
    __half* xs        = (__half*)alloc((size_t)N_NODES * IN_CH * sizeof(__half));  // reused as y2
    __half* bufA      = (__half*)alloc((size_t)N_NODES * HID * sizeof(__half));    // y1
    __half* bufH      = (__half*)alloc((size_t)N_NODES * HID * sizeof(__half));    // hs = dinv*h
    alloc(32 * 1024);  // pad for OOB tile reads in last GEMM block
    __half* bufB = xs;  // xs dead after agg1

    const int NGEMM = (N_NODES + 63) / 64;  // 1563
    const int HALF_BLKS = 50000 / 4;        // 12500 agg blocks per half

    // CSR build: hist -> bases(+wprep) -> binscatter -> bucket(+cast)
    hipMemsetAsync(btot, 0, (size_t)NBUCK * sizeof(int), stream);
    hipLaunchKernelGGL(k_hist, dim3(BBLK), dim3(512), 0, stream, e_dst, btot);
    hipLaunchKernelGGL(k_bases, dim3(17), dim3(1024), 0, stream, btot, bbase, bcur,
                       W1, Wmu, Wls, W1t, Wct);
    hipLaunchKernelGGL(k_binscatter, dim3(BBLK), dim3(512), 0, stream, e_src, e_dst, bcur, binned);
    hipLaunchKernelGGL(k_bucket, dim3(NBUCK), dim3(256), 0, stream, binned, bbase,
                       row_start, dinv, csr_src, x, xs);
    // layer 1 (agg split for diagnostics)
    hipLaunchKernelGGL(k_agg, dim3(HALF_BLKS), dim3(256), 0, stream, xs, bufA, csr_src, row_start, dinv, 0);
    hipLaunchKernelGGL(k_agg, dim3(HALF_BLKS), dim3(256), 0, stream, xs, bufA, csr_src, row_start, dinv, 50000);
    hipLaunchKernelGGL(k_gemm1, dim3(NGEMM), dim3(256), 0, stream, bufA, W1t, b1, dinv, bufH);
    // layers 2+3
    hipLaunchKernelGGL(k_agg, dim3(HALF_BLKS), dim3(256), 0, stream, bufH, bufB, csr_src, row_start, dinv, 0);
    hipLaunchKernelGGL(k_agg, dim3(HALF_BLKS), dim3(256), 0, stream, bufH, bufB, csr_src, row_start, dinv, 50000);
    hipLaunchKernelGGL(k_gemm2, dim3(NGEMM), dim3(256), 0, stream, bufB, Wct, bmu, bls, out);
}